// Round 3
// baseline (1263.908 us; speedup 1.0000x reference)
//
#include <hip/hip_runtime.h>

#define NSAMP 32768
#define INB   4
#define HIDN  4
#define CHN   2
#define OUTD  10
#define NPIX  196
#define NMID  194
#define BLK   256
#define NBLK  (NSAMP / BLK)            /* 128 blocks, one sample per thread */
#define INV_ROWS 1.52587890625e-05f    /* 1 / (N*CH) = 1/65536 */
#define BN_EPS 1e-5f

__device__ __forceinline__ float xcomp(const float4& v, int j) {
    return j == 0 ? v.x : j == 1 ? v.y : j == 2 ? v.z : v.w;
}

// One middle contraction step + batch-norm with a grid-wide stats reduction.
// stats slot t: [8] floats (sum[h], sumsq[h]); cnt[t]: arrival counter.
__device__ __forceinline__ void mid_step(
    int t, const float xv[INB], float y[CHN][HIDN],
    const float* __restrict__ wm,
    const float gm[HIDN], const float bt[HIDN],
    float* __restrict__ stats, unsigned int* __restrict__ cnt,
    float (*pb)[8], int tid, unsigned int nblk)
{
    const float* w = wm + (long)t * (HIDN * INB * HIDN * CHN);  // 128 floats, uniform addr
    float yn0[HIDN] = {0.f, 0.f, 0.f, 0.f};
    float yn1[HIDN] = {0.f, 0.f, 0.f, 0.f};
#pragma unroll
    for (int r = 0; r < HIDN; ++r) {
#pragma unroll
        for (int i = 0; i < INB; ++i) {
            float p0 = y[0][r] * xv[i];
            float p1 = y[1][r] * xv[i];
            const float* wri = w + r * (INB * HIDN * CHN) + i * (HIDN * CHN);
#pragma unroll
            for (int h = 0; h < HIDN; ++h) {
                yn0[h] = fmaf(p0, wri[h * CHN + 0], yn0[h]);
                yn1[h] = fmaf(p1, wri[h * CHN + 1], yn1[h]);
            }
        }
    }
    // per-thread partials: sum and sumsq per h over both channels
    float red[8];
#pragma unroll
    for (int h = 0; h < HIDN; ++h) {
        red[h]     = yn0[h] + yn1[h];
        red[4 + h] = yn0[h] * yn0[h] + yn1[h] * yn1[h];
    }
    // wave(64)-level reduce
#pragma unroll
    for (int j = 0; j < 8; ++j) {
#pragma unroll
        for (int off = 32; off > 0; off >>= 1)
            red[j] += __shfl_down(red[j], off);
    }
    int wv = tid >> 6;
    if ((tid & 63) == 0) {
#pragma unroll
        for (int j = 0; j < 8; ++j) pb[wv][j] = red[j];
    }
    __syncthreads();
    if (tid < 8) {
        float s = pb[0][tid] + pb[1][tid] + pb[2][tid] + pb[3][tid];
        atomicAdd(&stats[(long)t * 8 + tid], s);   // device-scope by default
    }
    __syncthreads();  // barrier drains vmcnt -> this block's atomics are complete
    if (tid == 0) {
        __hip_atomic_fetch_add(&cnt[t], 1u, __ATOMIC_RELEASE, __HIP_MEMORY_SCOPE_AGENT);
        while (__hip_atomic_load(&cnt[t], __ATOMIC_ACQUIRE, __HIP_MEMORY_SCOPE_AGENT) < nblk)
            __builtin_amdgcn_s_sleep(2);
    }
    __syncthreads();
    // everyone reads the 8 finished stats (agent-scope loads: bypass stale L1)
    float sm[8];
#pragma unroll
    for (int j = 0; j < 8; ++j)
        sm[j] = __hip_atomic_load(&stats[(long)t * 8 + j], __ATOMIC_RELAXED,
                                  __HIP_MEMORY_SCOPE_AGENT);
#pragma unroll
    for (int h = 0; h < HIDN; ++h) {
        float m  = sm[h] * INV_ROWS;
        float v  = fmaf(-m, m, sm[4 + h] * INV_ROWS);   // biased var
        float is = rsqrtf(v + BN_EPS) * gm[h];
        float sh = bt[h] - m * is;                      // (x-m)*inv*g+b = x*is + sh
        y[0][h] = fmaf(yn0[h], is, sh);
        y[1][h] = fmaf(yn1[h], is, sh);
    }
}

__global__ __launch_bounds__(BLK, 1)
void ttbn_main(const float* __restrict__ x,  const float* __restrict__ wf,
               const float* __restrict__ wm, const float* __restrict__ wl,
               const float* __restrict__ gamma, const float* __restrict__ beta,
               float* __restrict__ out, float* __restrict__ stats,
               unsigned int* __restrict__ cnt)
{
    __shared__ float pb[BLK / 64][8];
    const int tid = threadIdx.x;
    const int n   = blockIdx.x * BLK + tid;
    const unsigned int nblk = gridDim.x;

    float gm[HIDN], bt[HIDN];
#pragma unroll
    for (int h = 0; h < HIDN; ++h) { gm[h] = gamma[h]; bt[h] = beta[h]; }

    const float* xn = x + (long)n * (INB * NPIX);
    float4 xg[INB][4];            // 16 pixels x 4 bonds, full-line register prefetch
    float y[CHN][HIDN];

    // ---------------- group 0: pixels 0..15 ----------------
#pragma unroll
    for (int i = 0; i < INB; ++i)
#pragma unroll
        for (int q = 0; q < 4; ++q)
            xg[i][q] = *reinterpret_cast<const float4*>(xn + i * NPIX + q * 4);

    {   // pixel 0: y[c][h] = sum_i x_i * wf[i,h,c]   (no BN)
#pragma unroll
        for (int c = 0; c < CHN; ++c)
#pragma unroll
            for (int h = 0; h < HIDN; ++h) {
                float acc = 0.f;
#pragma unroll
                for (int i = 0; i < INB; ++i)
                    acc = fmaf(xcomp(xg[i][0], 0), wf[i * (HIDN * CHN) + h * CHN + c], acc);
                y[c][h] = acc;
            }
    }
#pragma unroll
    for (int sl = 1; sl < 16; ++sl) {
        float xv[INB];
#pragma unroll
        for (int i = 0; i < INB; ++i) xv[i] = xcomp(xg[i][sl / 4], sl & 3);
        mid_step(sl - 1, xv, y, wm, gm, bt, stats, cnt, pb, tid, nblk);
    }

    // ---------------- groups 1..11: pixels 16g..16g+15 ----------------
#pragma unroll 1
    for (int g = 1; g < 12; ++g) {
#pragma unroll
        for (int i = 0; i < INB; ++i)
#pragma unroll
            for (int q = 0; q < 4; ++q)
                xg[i][q] = *reinterpret_cast<const float4*>(xn + i * NPIX + g * 16 + q * 4);
#pragma unroll
        for (int sl = 0; sl < 16; ++sl) {
            float xv[INB];
#pragma unroll
            for (int i = 0; i < INB; ++i) xv[i] = xcomp(xg[i][sl / 4], sl & 3);
            mid_step(g * 16 + sl - 1, xv, y, wm, gm, bt, stats, cnt, pb, tid, nblk);
        }
    }

    // ---------------- group 12: pixels 192..195 ----------------
#pragma unroll
    for (int i = 0; i < INB; ++i)
        xg[i][0] = *reinterpret_cast<const float4*>(xn + i * NPIX + 192);
#pragma unroll
    for (int sl = 0; sl < 3; ++sl) {   // pixels 192,193,194 -> t = 191..193
        float xv[INB];
#pragma unroll
        for (int i = 0; i < INB; ++i) xv[i] = xcomp(xg[i][0], sl);
        mid_step(191 + sl, xv, y, wm, gm, bt, stats, cnt, pb, tid, nblk);
    }
    {   // pixel 195: out[n,0,c,o] = sum_{r,i} y[c][r]*x_i*wl[r,i,o,c]
        float xv[INB];
#pragma unroll
        for (int i = 0; i < INB; ++i) xv[i] = xcomp(xg[i][0], 3);
        float o0[OUTD], o1[OUTD];
#pragma unroll
        for (int od = 0; od < OUTD; ++od) { o0[od] = 0.f; o1[od] = 0.f; }
#pragma unroll
        for (int r = 0; r < HIDN; ++r)
#pragma unroll
            for (int i = 0; i < INB; ++i) {
                float p0 = y[0][r] * xv[i];
                float p1 = y[1][r] * xv[i];
                const float* wri = wl + r * (INB * OUTD * CHN) + i * (OUTD * CHN);
#pragma unroll
                for (int od = 0; od < OUTD; ++od) {
                    o0[od] = fmaf(p0, wri[od * CHN + 0], o0[od]);
                    o1[od] = fmaf(p1, wri[od * CHN + 1], o1[od]);
                }
            }
        float tmp[20];
#pragma unroll
        for (int od = 0; od < OUTD; ++od) { tmp[od] = o0[od]; tmp[10 + od] = o1[od]; }
        float4* o4 = reinterpret_cast<float4*>(out + (long)n * (CHN * OUTD));
#pragma unroll
        for (int q = 0; q < 5; ++q)
            o4[q] = make_float4(tmp[q * 4], tmp[q * 4 + 1], tmp[q * 4 + 2], tmp[q * 4 + 3]);
    }
}

extern "C" void kernel_launch(void* const* d_in, const int* in_sizes, int n_in,
                              void* d_out, int out_size, void* d_ws, size_t ws_size,
                              hipStream_t stream) {
    const float* x     = (const float*)d_in[0];
    const float* wf    = (const float*)d_in[1];
    const float* wm    = (const float*)d_in[2];
    const float* wl    = (const float*)d_in[3];
    const float* gamma = (const float*)d_in[4];
    const float* beta  = (const float*)d_in[5];
    float*       out   = (float*)d_out;

    // ws layout: stats[NMID][8] floats, then cnt[NMID] u32. Zero each call
    // (graph-capturable memset node) -> deterministic across replays.
    const size_t stats_bytes = (size_t)NMID * 8 * sizeof(float);
    const size_t cnt_bytes   = (size_t)NMID * sizeof(unsigned int);
    float*        stats = (float*)d_ws;
    unsigned int* cnt   = (unsigned int*)((char*)d_ws + stats_bytes);
    hipMemsetAsync(d_ws, 0, stats_bytes + cnt_bytes, stream);

    void* args[] = { &x, &wf, &wm, &wl, &gamma, &beta, &out, &stats, &cnt };
    hipLaunchCooperativeKernel((void*)ttbn_main, dim3(NBLK), dim3(BLK),
                               args, 0, stream);
}

// Round 4
// 1041.741 us; speedup vs baseline: 1.2133x; 1.2133x over previous
//
#include <hip/hip_runtime.h>

#define NSAMP 32768
#define INB   4
#define HIDN  4
#define CHN   2
#define OUTD  10
#define NPIX  196
#define NMID  194
#define BLK   256
#define SPT   2                        /* samples per thread */
#define NBLK  (NSAMP / (BLK * SPT))    /* 64 blocks */
#define INV_ROWS 1.52587890625e-05f    /* 1 / (N*CH) = 1/65536 */
#define BN_EPS 1e-5f
#define LINEF 32                       /* 128B cacheline in floats */
/* ws layout: per step t, 9 cachelines: j=0..7 stat words (sum[h],sumsq[h]),
   j=8 arrival counter. One word per line -> atomic streams don't share lines. */
#define WS_FLOATS ((size_t)NMID * 9 * LINEF)

__device__ __forceinline__ float xcomp(const float4& v, int j) {
    return j == 0 ? v.x : j == 1 ? v.y : j == 2 ? v.z : v.w;
}

__device__ __forceinline__ void mid_step(
    int t, const float xv[SPT][INB], float y[SPT][CHN][HIDN],
    const float* __restrict__ wm,
    const float gm[HIDN], const float bt[HIDN],
    float* __restrict__ ws, float (*pb)[8], int tid, unsigned int nblk)
{
    const float* w = wm + (long)t * (HIDN * INB * HIDN * CHN);  // 128 floats, uniform
    float yn[SPT][CHN][HIDN];
#pragma unroll
    for (int s = 0; s < SPT; ++s)
#pragma unroll
        for (int c = 0; c < CHN; ++c)
#pragma unroll
            for (int h = 0; h < HIDN; ++h) yn[s][c][h] = 0.f;

#pragma unroll
    for (int s = 0; s < SPT; ++s)
#pragma unroll
        for (int r = 0; r < HIDN; ++r)
#pragma unroll
            for (int i = 0; i < INB; ++i) {
                float p0 = y[s][0][r] * xv[s][i];
                float p1 = y[s][1][r] * xv[s][i];
                const float* wri = w + r * (INB * HIDN * CHN) + i * (HIDN * CHN);
#pragma unroll
                for (int h = 0; h < HIDN; ++h) {
                    yn[s][0][h] = fmaf(p0, wri[h * CHN + 0], yn[s][0][h]);
                    yn[s][1][h] = fmaf(p1, wri[h * CHN + 1], yn[s][1][h]);
                }
            }
    // per-thread partials: sum / sumsq per h over samples+channels
    float red[8];
#pragma unroll
    for (int h = 0; h < HIDN; ++h) {
        float sm = 0.f, sq = 0.f;
#pragma unroll
        for (int s = 0; s < SPT; ++s) {
            sm += yn[s][0][h] + yn[s][1][h];
            sq += yn[s][0][h] * yn[s][0][h] + yn[s][1][h] * yn[s][1][h];
        }
        red[h] = sm; red[4 + h] = sq;
    }
    // wave(64) reduce
#pragma unroll
    for (int j = 0; j < 8; ++j)
#pragma unroll
        for (int off = 32; off > 0; off >>= 1)
            red[j] += __shfl_down(red[j], off);
    int wv = tid >> 6;
    if ((tid & 63) == 0) {
#pragma unroll
        for (int j = 0; j < 8; ++j) pb[wv][j] = red[j];
    }
    __syncthreads();
    float* sl = ws + (size_t)t * 9 * LINEF;
    if (tid < 8) {
        float s = pb[0][tid] + pb[1][tid] + pb[2][tid] + pb[3][tid];
        atomicAdd(&sl[tid * LINEF], s);      // 8 parallel lines, no shared-line serialize
    }
    __syncthreads();  // drains this block's atomics before the arrival release
    unsigned int* cnt = (unsigned int*)(sl + 8 * LINEF);
    if (tid == 0) {
        __hip_atomic_fetch_add(cnt, 1u, __ATOMIC_RELEASE, __HIP_MEMORY_SCOPE_AGENT);
        while (__hip_atomic_load(cnt, __ATOMIC_ACQUIRE, __HIP_MEMORY_SCOPE_AGENT) < nblk)
            __builtin_amdgcn_s_sleep(1);
    }
    __syncthreads();
    float sm[8];
#pragma unroll
    for (int j = 0; j < 8; ++j)
        sm[j] = __hip_atomic_load(&sl[j * LINEF], __ATOMIC_RELAXED,
                                  __HIP_MEMORY_SCOPE_AGENT);
#pragma unroll
    for (int h = 0; h < HIDN; ++h) {
        float m  = sm[h] * INV_ROWS;
        float v  = fmaf(-m, m, sm[4 + h] * INV_ROWS);
        float is = rsqrtf(v + BN_EPS) * gm[h];
        float sh = bt[h] - m * is;
#pragma unroll
        for (int s = 0; s < SPT; ++s) {
            y[s][0][h] = fmaf(yn[s][0][h], is, sh);
            y[s][1][h] = fmaf(yn[s][1][h], is, sh);
        }
    }
}

__global__ __launch_bounds__(BLK, 1)
void ttbn_main(const float* __restrict__ x,  const float* __restrict__ wf,
               const float* __restrict__ wm, const float* __restrict__ wl,
               const float* __restrict__ gamma, const float* __restrict__ beta,
               float* __restrict__ out, float* __restrict__ ws)
{
    __shared__ float pb[BLK / 64][8];
    const int tid = threadIdx.x;
    const unsigned int nblk = gridDim.x;

    float gm[HIDN], bt[HIDN];
#pragma unroll
    for (int h = 0; h < HIDN; ++h) { gm[h] = gamma[h]; bt[h] = beta[h]; }

    const float* xn[SPT];
    long nidx[SPT];
#pragma unroll
    for (int s = 0; s < SPT; ++s) {
        nidx[s] = (long)blockIdx.x * (BLK * SPT) + s * BLK + tid;
        xn[s]   = x + nidx[s] * (INB * NPIX);
    }

    float4 xg[SPT][INB];          // 4 pixels x 4 bonds x SPT samples
    float  y[SPT][CHN][HIDN];

    // ---- group 0: pixels 0..3 ----
#pragma unroll
    for (int s = 0; s < SPT; ++s)
#pragma unroll
        for (int i = 0; i < INB; ++i)
            xg[s][i] = *reinterpret_cast<const float4*>(xn[s] + i * NPIX);

#pragma unroll
    for (int s = 0; s < SPT; ++s)
#pragma unroll
        for (int c = 0; c < CHN; ++c)
#pragma unroll
            for (int h = 0; h < HIDN; ++h) {
                float acc = 0.f;
#pragma unroll
                for (int i = 0; i < INB; ++i)
                    acc = fmaf(xg[s][i].x, wf[i * (HIDN * CHN) + h * CHN + c], acc);
                y[s][c][h] = acc;
            }
#pragma unroll
    for (int slp = 1; slp < 4; ++slp) {
        float xv[SPT][INB];
#pragma unroll
        for (int s = 0; s < SPT; ++s)
#pragma unroll
            for (int i = 0; i < INB; ++i) xv[s][i] = xcomp(xg[s][i], slp);
        mid_step(slp - 1, xv, y, wm, gm, bt, ws, pb, tid, nblk);
    }

    // ---- groups 1..47: pixels 4g..4g+3 ----
#pragma unroll 1
    for (int g = 1; g < 48; ++g) {
#pragma unroll
        for (int s = 0; s < SPT; ++s)
#pragma unroll
            for (int i = 0; i < INB; ++i)
                xg[s][i] = *reinterpret_cast<const float4*>(xn[s] + i * NPIX + g * 4);
#pragma unroll
        for (int slp = 0; slp < 4; ++slp) {
            float xv[SPT][INB];
#pragma unroll
            for (int s = 0; s < SPT; ++s)
#pragma unroll
                for (int i = 0; i < INB; ++i) xv[s][i] = xcomp(xg[s][i], slp);
            mid_step(g * 4 + slp - 1, xv, y, wm, gm, bt, ws, pb, tid, nblk);
        }
    }

    // ---- group 48: pixels 192..195 ----
#pragma unroll
    for (int s = 0; s < SPT; ++s)
#pragma unroll
        for (int i = 0; i < INB; ++i)
            xg[s][i] = *reinterpret_cast<const float4*>(xn[s] + i * NPIX + 192);
#pragma unroll
    for (int slp = 0; slp < 3; ++slp) {   // pixels 192..194 -> t = 191..193
        float xv[SPT][INB];
#pragma unroll
        for (int s = 0; s < SPT; ++s)
#pragma unroll
            for (int i = 0; i < INB; ++i) xv[s][i] = xcomp(xg[s][i], slp);
        mid_step(191 + slp, xv, y, wm, gm, bt, ws, pb, tid, nblk);
    }
    // pixel 195: out[n,0,c,o] = sum_{r,i} y[c][r]*x_i*wl[r,i,o,c]
#pragma unroll
    for (int s = 0; s < SPT; ++s) {
        float xv[INB];
#pragma unroll
        for (int i = 0; i < INB; ++i) xv[i] = xg[s][i].w;
        float o0[OUTD], o1[OUTD];
#pragma unroll
        for (int od = 0; od < OUTD; ++od) { o0[od] = 0.f; o1[od] = 0.f; }
#pragma unroll
        for (int r = 0; r < HIDN; ++r)
#pragma unroll
            for (int i = 0; i < INB; ++i) {
                float p0 = y[s][0][r] * xv[i];
                float p1 = y[s][1][r] * xv[i];
                const float* wri = wl + r * (INB * OUTD * CHN) + i * (OUTD * CHN);
#pragma unroll
                for (int od = 0; od < OUTD; ++od) {
                    o0[od] = fmaf(p0, wri[od * CHN + 0], o0[od]);
                    o1[od] = fmaf(p1, wri[od * CHN + 1], o1[od]);
                }
            }
        float tmp[20];
#pragma unroll
        for (int od = 0; od < OUTD; ++od) { tmp[od] = o0[od]; tmp[10 + od] = o1[od]; }
        float4* o4 = reinterpret_cast<float4*>(out + nidx[s] * (CHN * OUTD));
#pragma unroll
        for (int q = 0; q < 5; ++q)
            o4[q] = make_float4(tmp[q * 4], tmp[q * 4 + 1], tmp[q * 4 + 2], tmp[q * 4 + 3]);
    }
}

extern "C" void kernel_launch(void* const* d_in, const int* in_sizes, int n_in,
                              void* d_out, int out_size, void* d_ws, size_t ws_size,
                              hipStream_t stream) {
    const float* x     = (const float*)d_in[0];
    const float* wf    = (const float*)d_in[1];
    const float* wm    = (const float*)d_in[2];
    const float* wl    = (const float*)d_in[3];
    const float* gamma = (const float*)d_in[4];
    const float* beta  = (const float*)d_in[5];
    float*       out   = (float*)d_out;
    float*       ws    = (float*)d_ws;

    hipMemsetAsync(d_ws, 0, WS_FLOATS * sizeof(float), stream);

    void* args[] = { &x, &wf, &wm, &wl, &gamma, &beta, &out, &ws };
    hipLaunchCooperativeKernel((void*)ttbn_main, dim3(NBLK), dim3(BLK),
                               args, 0, stream);
}

// Round 5
// 982.939 us; speedup vs baseline: 1.2858x; 1.0598x over previous
//
#include <hip/hip_runtime.h>

#define NSAMP 32768
#define INB   4
#define HIDN  4
#define CHN   2
#define OUTD  10
#define NPIX  196
#define NMID  194
#define BLK   256
#define SPT   2                        /* samples per thread */
#define NBLK  (NSAMP / (BLK * SPT))    /* 64 blocks */
#define INV_ROWS 1.52587890625e-05f    /* 1 / (N*CH) = 1/65536 */
#define BN_EPS 1e-5f
#define LINEF 32                       /* 128B cacheline in floats */
/* ws layout: per step t, 9 cachelines: j=0..7 stat words (sum[h],sumsq[h]),
   j=8 arrival counter. One word per line -> atomic streams don't share lines.
   All cross-block traffic is RELAXED device-scope atomics: they execute at the
   LLC (coherence point) regardless of ordering, so no acquire-invalidate /
   release-writeback L2 maintenance is ever emitted. Per-step slots -> no
   staleness or reset hazard. */
#define WS_FLOATS ((size_t)NMID * 9 * LINEF)

__device__ __forceinline__ float xcomp(const float4& v, int j) {
    return j == 0 ? v.x : j == 1 ? v.y : j == 2 ? v.z : v.w;
}

__device__ __forceinline__ void mid_step(
    int t, const float xv[SPT][INB], float y[SPT][CHN][HIDN],
    const float* __restrict__ wm,
    const float gm[HIDN], const float bt[HIDN],
    float* __restrict__ ws, float (*pb)[8], int tid, unsigned int nblk)
{
    const float* w = wm + (long)t * (HIDN * INB * HIDN * CHN);  // 128 floats, uniform
    float yn[SPT][CHN][HIDN];
#pragma unroll
    for (int s = 0; s < SPT; ++s)
#pragma unroll
        for (int c = 0; c < CHN; ++c)
#pragma unroll
            for (int h = 0; h < HIDN; ++h) yn[s][c][h] = 0.f;

#pragma unroll
    for (int s = 0; s < SPT; ++s)
#pragma unroll
        for (int r = 0; r < HIDN; ++r)
#pragma unroll
            for (int i = 0; i < INB; ++i) {
                float p0 = y[s][0][r] * xv[s][i];
                float p1 = y[s][1][r] * xv[s][i];
                const float* wri = w + r * (INB * HIDN * CHN) + i * (HIDN * CHN);
#pragma unroll
                for (int h = 0; h < HIDN; ++h) {
                    yn[s][0][h] = fmaf(p0, wri[h * CHN + 0], yn[s][0][h]);
                    yn[s][1][h] = fmaf(p1, wri[h * CHN + 1], yn[s][1][h]);
                }
            }
    // per-thread partials: sum / sumsq per h over samples+channels
    float red[8];
#pragma unroll
    for (int h = 0; h < HIDN; ++h) {
        float sm = 0.f, sq = 0.f;
#pragma unroll
        for (int s = 0; s < SPT; ++s) {
            sm += yn[s][0][h] + yn[s][1][h];
            sq += yn[s][0][h] * yn[s][0][h] + yn[s][1][h] * yn[s][1][h];
        }
        red[h] = sm; red[4 + h] = sq;
    }
    // wave(64) reduce
#pragma unroll
    for (int j = 0; j < 8; ++j)
#pragma unroll
        for (int off = 32; off > 0; off >>= 1)
            red[j] += __shfl_down(red[j], off);
    int wv = tid >> 6;
    if ((tid & 63) == 0) {
#pragma unroll
        for (int j = 0; j < 8; ++j) pb[wv][j] = red[j];
    }
    __syncthreads();                       // pb ready for wave 0
    float* slb = ws + (size_t)t * 9 * LINEF;
    unsigned int* cnt = (unsigned int*)(slb + 8 * LINEF);
    if (tid < 8) {
        float s = pb[0][tid] + pb[1][tid] + pb[2][tid] + pb[3][tid];
        atomicAdd(&slb[tid * LINEF], s);   // device-scope RMW at LLC, relaxed
    }
    if (tid == 0) {
        // wave-level drain: vmcnt covers lanes 1-7's stat atomics too
        asm volatile("s_waitcnt vmcnt(0)" ::: "memory");
        __hip_atomic_fetch_add(cnt, 1u, __ATOMIC_RELAXED, __HIP_MEMORY_SCOPE_AGENT);
        while (__hip_atomic_load(cnt, __ATOMIC_RELAXED, __HIP_MEMORY_SCOPE_AGENT) < nblk)
            __builtin_amdgcn_s_sleep(1);
    }
    __syncthreads();                       // holds waves 1-3 until poll done; fence
    float sm[8];
#pragma unroll
    for (int j = 0; j < 8; ++j)
        sm[j] = __hip_atomic_load(&slb[j * LINEF], __ATOMIC_RELAXED,
                                  __HIP_MEMORY_SCOPE_AGENT);
#pragma unroll
    for (int h = 0; h < HIDN; ++h) {
        float m  = sm[h] * INV_ROWS;
        float v  = fmaf(-m, m, sm[4 + h] * INV_ROWS);
        float is = rsqrtf(v + BN_EPS) * gm[h];
        float sh = bt[h] - m * is;
#pragma unroll
        for (int s = 0; s < SPT; ++s) {
            y[s][0][h] = fmaf(yn[s][0][h], is, sh);
            y[s][1][h] = fmaf(yn[s][1][h], is, sh);
        }
    }
}

__global__ __launch_bounds__(BLK, 1)
void ttbn_main(const float* __restrict__ x,  const float* __restrict__ wf,
               const float* __restrict__ wm, const float* __restrict__ wl,
               const float* __restrict__ gamma, const float* __restrict__ beta,
               float* __restrict__ out, float* __restrict__ ws)
{
    __shared__ float pb[BLK / 64][8];
    const int tid = threadIdx.x;
    const unsigned int nblk = gridDim.x;

    float gm[HIDN], bt[HIDN];
#pragma unroll
    for (int h = 0; h < HIDN; ++h) { gm[h] = gamma[h]; bt[h] = beta[h]; }

    const float* xn[SPT];
    long nidx[SPT];
#pragma unroll
    for (int s = 0; s < SPT; ++s) {
        nidx[s] = (long)blockIdx.x * (BLK * SPT) + s * BLK + tid;
        xn[s]   = x + nidx[s] * (INB * NPIX);
    }

    float4 xg[SPT][INB];          // 4 pixels x 4 bonds x SPT samples
    float  y[SPT][CHN][HIDN];

    // ---- group 0: pixels 0..3 ----
#pragma unroll
    for (int s = 0; s < SPT; ++s)
#pragma unroll
        for (int i = 0; i < INB; ++i)
            xg[s][i] = *reinterpret_cast<const float4*>(xn[s] + i * NPIX);

#pragma unroll
    for (int s = 0; s < SPT; ++s)
#pragma unroll
        for (int c = 0; c < CHN; ++c)
#pragma unroll
            for (int h = 0; h < HIDN; ++h) {
                float acc = 0.f;
#pragma unroll
                for (int i = 0; i < INB; ++i)
                    acc = fmaf(xg[s][i].x, wf[i * (HIDN * CHN) + h * CHN + c], acc);
                y[s][c][h] = acc;
            }
#pragma unroll
    for (int slp = 1; slp < 4; ++slp) {
        float xv[SPT][INB];
#pragma unroll
        for (int s = 0; s < SPT; ++s)
#pragma unroll
            for (int i = 0; i < INB; ++i) xv[s][i] = xcomp(xg[s][i], slp);
        mid_step(slp - 1, xv, y, wm, gm, bt, ws, pb, tid, nblk);
    }

    // ---- groups 1..47: pixels 4g..4g+3 ----
#pragma unroll 1
    for (int g = 1; g < 48; ++g) {
#pragma unroll
        for (int s = 0; s < SPT; ++s)
#pragma unroll
            for (int i = 0; i < INB; ++i)
                xg[s][i] = *reinterpret_cast<const float4*>(xn[s] + i * NPIX + g * 4);
#pragma unroll
        for (int slp = 0; slp < 4; ++slp) {
            float xv[SPT][INB];
#pragma unroll
            for (int s = 0; s < SPT; ++s)
#pragma unroll
                for (int i = 0; i < INB; ++i) xv[s][i] = xcomp(xg[s][i], slp);
            mid_step(g * 4 + slp - 1, xv, y, wm, gm, bt, ws, pb, tid, nblk);
        }
    }

    // ---- group 48: pixels 192..195 ----
#pragma unroll
    for (int s = 0; s < SPT; ++s)
#pragma unroll
        for (int i = 0; i < INB; ++i)
            xg[s][i] = *reinterpret_cast<const float4*>(xn[s] + i * NPIX + 192);
#pragma unroll
    for (int slp = 0; slp < 3; ++slp) {   // pixels 192..194 -> t = 191..193
        float xv[SPT][INB];
#pragma unroll
        for (int s = 0; s < SPT; ++s)
#pragma unroll
            for (int i = 0; i < INB; ++i) xv[s][i] = xcomp(xg[s][i], slp);
        mid_step(191 + slp, xv, y, wm, gm, bt, ws, pb, tid, nblk);
    }
    // pixel 195: out[n,0,c,o] = sum_{r,i} y[c][r]*x_i*wl[r,i,o,c]
#pragma unroll
    for (int s = 0; s < SPT; ++s) {
        float xv[INB];
#pragma unroll
        for (int i = 0; i < INB; ++i) xv[i] = xg[s][i].w;
        float o0[OUTD], o1[OUTD];
#pragma unroll
        for (int od = 0; od < OUTD; ++od) { o0[od] = 0.f; o1[od] = 0.f; }
#pragma unroll
        for (int r = 0; r < HIDN; ++r)
#pragma unroll
            for (int i = 0; i < INB; ++i) {
                float p0 = y[s][0][r] * xv[i];
                float p1 = y[s][1][r] * xv[i];
                const float* wri = wl + r * (INB * OUTD * CHN) + i * (OUTD * CHN);
#pragma unroll
                for (int od = 0; od < OUTD; ++od) {
                    o0[od] = fmaf(p0, wri[od * CHN + 0], o0[od]);
                    o1[od] = fmaf(p1, wri[od * CHN + 1], o1[od]);
                }
            }
        float tmp[20];
#pragma unroll
        for (int od = 0; od < OUTD; ++od) { tmp[od] = o0[od]; tmp[10 + od] = o1[od]; }
        float4* o4 = reinterpret_cast<float4*>(out + nidx[s] * (CHN * OUTD));
#pragma unroll
        for (int q = 0; q < 5; ++q)
            o4[q] = make_float4(tmp[q * 4], tmp[q * 4 + 1], tmp[q * 4 + 2], tmp[q * 4 + 3]);
    }
}

extern "C" void kernel_launch(void* const* d_in, const int* in_sizes, int n_in,
                              void* d_out, int out_size, void* d_ws, size_t ws_size,
                              hipStream_t stream) {
    const float* x     = (const float*)d_in[0];
    const float* wf    = (const float*)d_in[1];
    const float* wm    = (const float*)d_in[2];
    const float* wl    = (const float*)d_in[3];
    const float* gamma = (const float*)d_in[4];
    const float* beta  = (const float*)d_in[5];
    float*       out   = (float*)d_out;
    float*       ws    = (float*)d_ws;

    hipMemsetAsync(d_ws, 0, WS_FLOATS * sizeof(float), stream);

    void* args[] = { &x, &wf, &wm, &wl, &gamma, &beta, &out, &ws };
    hipLaunchCooperativeKernel((void*)ttbn_main, dim3(NBLK), dim3(BLK),
                               args, 0, stream);
}

// Round 6
// 936.841 us; speedup vs baseline: 1.3491x; 1.0492x over previous
//
#include <hip/hip_runtime.h>

#define NSAMP 32768
#define INB   4
#define HIDN  4
#define CHN   2
#define OUTD  10
#define NPIX  196
#define NMID  194
#define BLK   256
#define SPT   2                        /* samples per thread */
#define NBLK  (NSAMP / (BLK * SPT))    /* 64 blocks == wave width */
#define INV_ROWS 1.52587890625e-05f    /* 1 / (N*CH) = 1/65536 */
#define BN_EPS 1e-5f
#define SENT  0xFFFFFFFFFFFFFFFFull    /* NaN-pair sentinel, unreachable by finite math */
/* ws: slots[NMID][NBLK][4] u64 — 32B per block-slot, written once per step by
   4 relaxed agent-scope u64 stores (each 8B store commits atomically at the
   coherence point). Pollers read the same words: detection == data delivery.
   No RMW atomics, no arrival counter, no separate broadcast read. */
#define WS_BYTES ((size_t)NMID * NBLK * 4 * sizeof(unsigned long long))

__device__ __forceinline__ float xcomp(const float4& v, int j) {
    return j == 0 ? v.x : j == 1 ? v.y : j == 2 ? v.z : v.w;
}

__device__ __forceinline__ void mid_step(
    int t, const float xv[SPT][INB], float y[SPT][CHN][HIDN],
    const float* __restrict__ wm,
    const float gm[HIDN], const float bt[HIDN],
    unsigned long long* __restrict__ slots, float (*pb)[8], int tid)
{
    const float* w = wm + (long)t * (HIDN * INB * HIDN * CHN);  // 128 floats, uniform
    float yn[SPT][CHN][HIDN];
#pragma unroll
    for (int s = 0; s < SPT; ++s)
#pragma unroll
        for (int c = 0; c < CHN; ++c)
#pragma unroll
            for (int h = 0; h < HIDN; ++h) yn[s][c][h] = 0.f;

#pragma unroll
    for (int s = 0; s < SPT; ++s)
#pragma unroll
        for (int r = 0; r < HIDN; ++r)
#pragma unroll
            for (int i = 0; i < INB; ++i) {
                float p0 = y[s][0][r] * xv[s][i];
                float p1 = y[s][1][r] * xv[s][i];
                const float* wri = w + r * (INB * HIDN * CHN) + i * (HIDN * CHN);
#pragma unroll
                for (int h = 0; h < HIDN; ++h) {
                    yn[s][0][h] = fmaf(p0, wri[h * CHN + 0], yn[s][0][h]);
                    yn[s][1][h] = fmaf(p1, wri[h * CHN + 1], yn[s][1][h]);
                }
            }
    // per-thread partials: sum / sumsq per h over samples+channels
    float red[8];
#pragma unroll
    for (int h = 0; h < HIDN; ++h) {
        float sm = 0.f, sq = 0.f;
#pragma unroll
        for (int s = 0; s < SPT; ++s) {
            sm += yn[s][0][h] + yn[s][1][h];
            sq += yn[s][0][h] * yn[s][0][h] + yn[s][1][h] * yn[s][1][h];
        }
        red[h] = sm; red[4 + h] = sq;
    }
    // wave(64) reduce -> lane 0 of each wave
#pragma unroll
    for (int j = 0; j < 8; ++j)
#pragma unroll
        for (int off = 32; off > 0; off >>= 1)
            red[j] += __shfl_down(red[j], off);
    const int wv = tid >> 6, ln = tid & 63;
    if (ln == 0) {
#pragma unroll
        for (int j = 0; j < 8; ++j) pb[wv][j] = red[j];
    }
    __syncthreads();                       // pb ready
    // wave-0 lanes 0-3: combine 4 waves, store block partial (2 floats / lane)
    if (tid < 4) {
        float lo = pb[0][2 * tid]     + pb[1][2 * tid]     + pb[2][2 * tid]     + pb[3][2 * tid];
        float hi = pb[0][2 * tid + 1] + pb[1][2 * tid + 1] + pb[2][2 * tid + 1] + pb[3][2 * tid + 1];
        unsigned long long v = ((unsigned long long)__float_as_uint(hi) << 32)
                             |  (unsigned long long)__float_as_uint(lo);
        __hip_atomic_store(&slots[((size_t)t * NBLK + blockIdx.x) * 4 + tid], v,
                           __ATOMIC_RELAXED, __HIP_MEMORY_SCOPE_AGENT);
    }
    // every wave polls all NBLK slots: lane ln watches block ln's slot.
    const unsigned long long* ps = &slots[((size_t)t * NBLK + ln) * 4];
    unsigned long long q0, q1, q2, q3;
    do {
        q0 = __hip_atomic_load(&ps[0], __ATOMIC_RELAXED, __HIP_MEMORY_SCOPE_AGENT);
        q1 = __hip_atomic_load(&ps[1], __ATOMIC_RELAXED, __HIP_MEMORY_SCOPE_AGENT);
        q2 = __hip_atomic_load(&ps[2], __ATOMIC_RELAXED, __HIP_MEMORY_SCOPE_AGENT);
        q3 = __hip_atomic_load(&ps[3], __ATOMIC_RELAXED, __HIP_MEMORY_SCOPE_AGENT);
    } while (!__all(q0 != SENT && q1 != SENT && q2 != SENT && q3 != SENT));
    // lane ln now holds block ln's 8 partials; butterfly-sum across lanes
    float sm[8];
    sm[0] = __uint_as_float((unsigned)q0); sm[1] = __uint_as_float((unsigned)(q0 >> 32));
    sm[2] = __uint_as_float((unsigned)q1); sm[3] = __uint_as_float((unsigned)(q1 >> 32));
    sm[4] = __uint_as_float((unsigned)q2); sm[5] = __uint_as_float((unsigned)(q2 >> 32));
    sm[6] = __uint_as_float((unsigned)q3); sm[7] = __uint_as_float((unsigned)(q3 >> 32));
#pragma unroll
    for (int j = 0; j < 8; ++j)
#pragma unroll
        for (int off = 1; off < 64; off <<= 1)
            sm[j] += __shfl_xor(sm[j], off);
#pragma unroll
    for (int h = 0; h < HIDN; ++h) {
        float m  = sm[h] * INV_ROWS;
        float v  = fmaf(-m, m, sm[4 + h] * INV_ROWS);
        float is = rsqrtf(v + BN_EPS) * gm[h];
        float sh = bt[h] - m * is;
#pragma unroll
        for (int s = 0; s < SPT; ++s) {
            y[s][0][h] = fmaf(yn[s][0][h], is, sh);
            y[s][1][h] = fmaf(yn[s][1][h], is, sh);
        }
    }
}

__global__ __launch_bounds__(BLK, 1)
void ttbn_main(const float* __restrict__ x,  const float* __restrict__ wf,
               const float* __restrict__ wm, const float* __restrict__ wl,
               const float* __restrict__ gamma, const float* __restrict__ beta,
               float* __restrict__ out, unsigned long long* __restrict__ slots)
{
    __shared__ float pb[BLK / 64][8];
    const int tid = threadIdx.x;

    float gm[HIDN], bt[HIDN];
#pragma unroll
    for (int h = 0; h < HIDN; ++h) { gm[h] = gamma[h]; bt[h] = beta[h]; }

    const float* xn[SPT];
    long nidx[SPT];
#pragma unroll
    for (int s = 0; s < SPT; ++s) {
        nidx[s] = (long)blockIdx.x * (BLK * SPT) + s * BLK + tid;
        xn[s]   = x + nidx[s] * (INB * NPIX);
    }

    float4 xg[SPT][INB];          // 4 pixels x 4 bonds x SPT samples
    float  y[SPT][CHN][HIDN];

    // ---- group 0: pixels 0..3 ----
#pragma unroll
    for (int s = 0; s < SPT; ++s)
#pragma unroll
        for (int i = 0; i < INB; ++i)
            xg[s][i] = *reinterpret_cast<const float4*>(xn[s] + i * NPIX);

#pragma unroll
    for (int s = 0; s < SPT; ++s)
#pragma unroll
        for (int c = 0; c < CHN; ++c)
#pragma unroll
            for (int h = 0; h < HIDN; ++h) {
                float acc = 0.f;
#pragma unroll
                for (int i = 0; i < INB; ++i)
                    acc = fmaf(xg[s][i].x, wf[i * (HIDN * CHN) + h * CHN + c], acc);
                y[s][c][h] = acc;
            }
#pragma unroll
    for (int slp = 1; slp < 4; ++slp) {
        float xv[SPT][INB];
#pragma unroll
        for (int s = 0; s < SPT; ++s)
#pragma unroll
            for (int i = 0; i < INB; ++i) xv[s][i] = xcomp(xg[s][i], slp);
        mid_step(slp - 1, xv, y, wm, gm, bt, slots, pb, tid);
    }

    // ---- groups 1..47: pixels 4g..4g+3 ----
#pragma unroll 1
    for (int g = 1; g < 48; ++g) {
#pragma unroll
        for (int s = 0; s < SPT; ++s)
#pragma unroll
            for (int i = 0; i < INB; ++i)
                xg[s][i] = *reinterpret_cast<const float4*>(xn[s] + i * NPIX + g * 4);
#pragma unroll
        for (int slp = 0; slp < 4; ++slp) {
            float xv[SPT][INB];
#pragma unroll
            for (int s = 0; s < SPT; ++s)
#pragma unroll
                for (int i = 0; i < INB; ++i) xv[s][i] = xcomp(xg[s][i], slp);
            mid_step(g * 4 + slp - 1, xv, y, wm, gm, bt, slots, pb, tid);
        }
    }

    // ---- group 48: pixels 192..195 ----
#pragma unroll
    for (int s = 0; s < SPT; ++s)
#pragma unroll
        for (int i = 0; i < INB; ++i)
            xg[s][i] = *reinterpret_cast<const float4*>(xn[s] + i * NPIX + 192);
#pragma unroll
    for (int slp = 0; slp < 3; ++slp) {   // pixels 192..194 -> t = 191..193
        float xv[SPT][INB];
#pragma unroll
        for (int s = 0; s < SPT; ++s)
#pragma unroll
            for (int i = 0; i < INB; ++i) xv[s][i] = xcomp(xg[s][i], slp);
        mid_step(191 + slp, xv, y, wm, gm, bt, slots, pb, tid);
    }
    // pixel 195: out[n,0,c,o] = sum_{r,i} y[c][r]*x_i*wl[r,i,o,c]
#pragma unroll
    for (int s = 0; s < SPT; ++s) {
        float xv[INB];
#pragma unroll
        for (int i = 0; i < INB; ++i) xv[i] = xg[s][i].w;
        float o0[OUTD], o1[OUTD];
#pragma unroll
        for (int od = 0; od < OUTD; ++od) { o0[od] = 0.f; o1[od] = 0.f; }
#pragma unroll
        for (int r = 0; r < HIDN; ++r)
#pragma unroll
            for (int i = 0; i < INB; ++i) {
                float p0 = y[s][0][r] * xv[i];
                float p1 = y[s][1][r] * xv[i];
                const float* wri = wl + r * (INB * OUTD * CHN) + i * (OUTD * CHN);
#pragma unroll
                for (int od = 0; od < OUTD; ++od) {
                    o0[od] = fmaf(p0, wri[od * CHN + 0], o0[od]);
                    o1[od] = fmaf(p1, wri[od * CHN + 1], o1[od]);
                }
            }
        float tmp[20];
#pragma unroll
        for (int od = 0; od < OUTD; ++od) { tmp[od] = o0[od]; tmp[10 + od] = o1[od]; }
        float4* o4 = reinterpret_cast<float4*>(out + nidx[s] * (CHN * OUTD));
#pragma unroll
        for (int q = 0; q < 5; ++q)
            o4[q] = make_float4(tmp[q * 4], tmp[q * 4 + 1], tmp[q * 4 + 2], tmp[q * 4 + 3]);
    }
}

extern "C" void kernel_launch(void* const* d_in, const int* in_sizes, int n_in,
                              void* d_out, int out_size, void* d_ws, size_t ws_size,
                              hipStream_t stream) {
    const float* x     = (const float*)d_in[0];
    const float* wf    = (const float*)d_in[1];
    const float* wm    = (const float*)d_in[2];
    const float* wl    = (const float*)d_in[3];
    const float* gamma = (const float*)d_in[4];
    const float* beta  = (const float*)d_in[5];
    float*       out   = (float*)d_out;
    unsigned long long* slots = (unsigned long long*)d_ws;

    // sentinel-fill the slot array (0xFF bytes == SENT); stream-ordered before kernel
    hipMemsetAsync(d_ws, 0xFF, WS_BYTES, stream);

    void* args[] = { &x, &wf, &wm, &wl, &gamma, &beta, &out, &slots };
    hipLaunchCooperativeKernel((void*)ttbn_main, dim3(NBLK), dim3(BLK),
                               args, 0, stream);
}